// Round 12
// baseline (1477.300 us; speedup 1.0000x reference)
//
#include <hip/hip_runtime.h>

typedef unsigned short u16;
typedef unsigned int   u32;

static __device__ __forceinline__ float sigf (float x){ return 1.0f/(1.0f+__expf(-x)); }
static __device__ __forceinline__ float tanh_(float x){ return 2.0f/(1.0f+__expf(-2.0f*x)) - 1.0f; }

// sizes
#define NM 2730            // 273*10 distinct (t, j=b%10) rows
#define N_O0 878080        // 245*128*28
#define N_O3 978432        // 273*128*28

static __device__ __forceinline__ int dot4(u32 a, u32 b, int acc){
#if __has_builtin(__builtin_amdgcn_sdot4)
  return __builtin_amdgcn_sdot4((int)a, (int)b, acc, false);
#else
  int s = acc;
  #pragma unroll
  for(int i=0;i<4;i++){
    int av = (int)((signed char)((a >> (8*i)) & 0xffu));
    int bv = (int)((signed char)((b >> (8*i)) & 0xffu));
    s += av*bv;
  }
  return s;
#endif
}

// ---- fused prep: xT + 6 transposes + Whh row scales ----
__global__ __launch_bounds__(256) void k_prep(
    const float* __restrict__ x,     float* __restrict__ xT,
    const float* __restrict__ wi0,   float* __restrict__ wT0,
    const float* __restrict__ wi1,   float* __restrict__ wT1,
    const float* __restrict__ wi2,   float* __restrict__ wT2,
    const float* __restrict__ wi3,   float* __restrict__ wT3,
    const float* __restrict__ lw,    float* __restrict__ lwT,
    const float* __restrict__ sw,    float* __restrict__ swT,
    const float* __restrict__ h0, const float* __restrict__ h1,
    const float* __restrict__ h2, const float* __restrict__ h3,
    float* __restrict__ zsc){
  int i = blockIdx.x*256 + threadIdx.x;
  if(i < 38400){                    // xT
    int t = i >> 7, b = i & 127;
    xT[i] = x[b*300 + t];
    return;
  }
  i -= 38400;
  if(i < 50176){ int c=i/1024, r=i-c*1024; wT0[i] = wi0[r*49 + c];  return; }
  i -= 50176;
  if(i < 262144){ int c=i>>10, r=i&1023; wT1[i] = wi1[r*256 + c];   return; }
  i -= 262144;
  if(i < 262144){ int c=i>>10, r=i&1023; wT2[i] = wi2[r*256 + c];   return; }
  i -= 262144;
  if(i < 262144){ int c=i>>10, r=i&1023; wT3[i] = wi3[r*256 + c];   return; }
  i -= 262144;
  if(i < 65536){ int c=i>>8, r=i&255; lwT[i] = lw[r*256 + c];       return; }
  i -= 65536;
  if(i < 7168){ int c=i/28, r=i-c*28; swT[i] = sw[r*256 + c];       return; }
  i -= 7168;
  if(i < 4096){                     // per-row absmax scale (int8)
    int l = i >> 10, r = i & 1023;
    const float* W = (l==0)?h0:(l==1)?h1:(l==2)?h2:h3;
    const float4* p = (const float4*)(W + (size_t)r*256);
    float m = 0.f;
    #pragma unroll 8
    for(int q=0;q<64;q++){
      float4 v = p[q];
      m = fmaxf(m, fmaxf(fmaxf(fabsf(v.x),fabsf(v.y)), fmaxf(fabsf(v.z),fabsf(v.w))));
    }
    zsc[i] = fmaxf(m, 1e-20f) * (1.0f/16129.0f);   // rowmax/(127*127)
  }
}

// ---- fused int8 pack + ES scan ----
// pack layout for scan9: u32 index w (per layer): dw=w&3, tid=(w>>2)&511,
// combo=w>>11 (rr=combo>>2, q=combo&3); thread tid: kg=tid>>2, js=tid&3;
// row=rr*128+kg ; k0=js*64+q*16+dw*4
__global__ __launch_bounds__(256) void k_packes(
    const float* __restrict__ h0, const float* __restrict__ h1,
    const float* __restrict__ h2, const float* __restrict__ h3,
    const float* __restrict__ zsc, u32* __restrict__ W8,
    const float* __restrict__ xT, const float* __restrict__ alpha,
    const float* __restrict__ gamma, const float* __restrict__ iseas,
    float* __restrict__ ST, float* __restrict__ lvlT){
  if(blockIdx.x < 1024){
    int i = blockIdx.x*256 + threadIdx.x;      // 0..262143
    int l = i >> 16;
    int w = i & 65535;
    int dw  = w & 3;
    int tid = (w >> 2) & 511;
    int combo = w >> 11;
    int kg = tid >> 2, js = tid & 3;
    int rr = combo >> 2, q = combo & 3;
    int row = rr*128 + kg;
    int k0  = js*64 + q*16 + dw*4;
    const float* W = (l==0)?h0:(l==1)?h1:(l==2)?h2:h3;
    float inv = 1.0f / (zsc[l*1024 + row] * 127.0f);
    u32 out = 0;
    #pragma unroll
    for(int b=0;b<4;b++){
      float v = W[(size_t)row*256 + k0 + b];
      int q8 = max(-127, min(127, __float2int_rn(v * inv)));
      out |= ((u32)(q8 & 0xff)) << (8*b);
    }
    W8[i] = out;
    return;
  }
  // ES scan (block 1024, threads 0..127)
  int b = threadIdx.x;
  if(b >= 128) return;
  float a = sigf(alpha[b]);
  float g = sigf(gamma[b]);
  float S0[7];
  #pragma unroll
  for(int i=0;i<7;i++){ S0[i] = __expf(iseas[b*7+i]); ST[i*128+b] = S0[i]; }
  ST[7*128+b] = S0[0];
  float q0=S0[1],q1=S0[2],q2=S0[3],q3=S0[4],q4=S0[5],q5=S0[6],q6=S0[0];
  float lvl = xT[b]/S0[0];
  lvlT[b] = lvl;
  for(int t=1;t<300;t++){
    float xt = xT[t*128+b];
    float s  = q0;
    lvl = a*(xt/s) + (1.0f-a)*lvl;
    float sn = g*(xt/lvl) + (1.0f-g)*s;
    q0=q1;q1=q2;q2=q3;q3=q4;q4=q5;q5=q6;q6=sn;
    lvlT[t*128+b]   = lvl;
    ST[(t+7)*128+b] = sn;
  }
}

// ---- gemm for layer 1: window_input built on the fly in staging ----
__global__ __launch_bounds__(256) void k_gemm1(
    const float* __restrict__ xT, const float* __restrict__ ST,
    const float* __restrict__ lvlT, const float* __restrict__ cats,
    const float* __restrict__ mp,
    const float* __restrict__ WT,   // [49][1024] f32
    const float* __restrict__ bias, // [1024] f32
    float* __restrict__ Z){
  __shared__ float Xs[8][52];
  const int tid = threadIdx.x;
  const int m0 = blockIdx.x*8;
  for(int idx=tid; idx<8*49; idx+=256){
    int p = idx/49, f = idx - p*49;
    int m = m0+p;
    float v = 0.f;
    if(m < NM){
      int tt = m/10, jj = m - (m/10)*10;
      if(f < 28){
        int c = tt + f;
        v = xT[c*128 + jj] / ST[c*128 + jj] / lvlT[(tt+27)*128 + jj];
      } else if(f < 48){
        v = cats[jj*20 + (f-28)];
      } else {
        v = mp[0];
      }
    }
    Xs[p][f] = v;
  }
  __syncthreads();
  float acc0[8], acc1[8], acc2[8], acc3[8];
  {
    float b0 = bias[tid];
    float b1 = bias[tid+256];
    float b2 = bias[tid+512];
    float b3 = bias[tid+768];
    #pragma unroll
    for(int p=0;p<8;p++){ acc0[p]=b0; acc1[p]=b1; acc2[p]=b2; acc3[p]=b3; }
  }
  #pragma unroll 7
  for(int f=0; f<49; f++){
    float w0 = WT[f*1024 + tid      ];
    float w1 = WT[f*1024 + tid+256  ];
    float w2 = WT[f*1024 + tid+512  ];
    float w3 = WT[f*1024 + tid+768  ];
    #pragma unroll
    for(int p=0;p<8;p++){
      float xv = Xs[p][f];
      acc0[p] += w0*xv; acc1[p] += w1*xv; acc2[p] += w2*xv; acc3[p] += w3*xv;
    }
  }
  for(int p=0;p<8;p++){
    int m = m0+p;
    if(m < NM){
      float* zb = Z + m*1024 + tid;
      zb[0]=acc0[p]; zb[256]=acc1[p]; zb[512]=acc2[p]; zb[768]=acc3[p];
    }
  }
}

// ---- batched xz = X @ WihT + b (F=256 layers) ----
__global__ __launch_bounds__(256) void k_gemm(const float* __restrict__ X,
                                              const float* __restrict__ WT,   // [256][1024] f32
                                              const float* __restrict__ bias, // [1024] f32
                                              float* __restrict__ Z){
  __shared__ float Xs[8][256];
  const int tid = threadIdx.x;
  const int m0 = blockIdx.x*8;
  for(int p=0;p<8;p++){
    int m = m0+p;
    Xs[p][tid] = (m < NM) ? X[m*256+tid] : 0.0f;
  }
  __syncthreads();
  float acc0[8], acc1[8], acc2[8], acc3[8];
  {
    float b0 = bias[tid];
    float b1 = bias[tid+256];
    float b2 = bias[tid+512];
    float b3 = bias[tid+768];
    #pragma unroll
    for(int p=0;p<8;p++){ acc0[p]=b0; acc1[p]=b1; acc2[p]=b2; acc3[p]=b3; }
  }
  #pragma unroll 4
  for(int f=0; f<256; f++){
    float w0 = WT[f*1024 + tid      ];
    float w1 = WT[f*1024 + tid+256  ];
    float w2 = WT[f*1024 + tid+512  ];
    float w3 = WT[f*1024 + tid+768  ];
    #pragma unroll
    for(int p=0;p<8;p++){
      float xv = Xs[p][f];
      acc0[p] += w0*xv; acc1[p] += w1*xv; acc2[p] += w2*xv; acc3[p] += w3*xv;
    }
  }
  for(int p=0;p<8;p++){
    int m = m0+p;
    if(m < NM){
      float* zb = Z + m*1024 + tid;
      zb[0]=acc0[p]; zb[256]=acc1[p]; zb[512]=acc2[p]; zb[768]=acc3[p];
    }
  }
}

// ---- LSTM scan v9: int8 sdot4; thread (kg=tid>>2, js=tid&3); lane-quad
// shfl reduction (no zp LDS); js==0 lanes combine 2 units (c-state +
// row scales in regs); double-buffered h (512B) -> ONE barrier/step.
// NC of 32 weight combos LDS-cached (dynamic), rest streamed from L2.
template<int NC>
__global__ __launch_bounds__(512) void k_scan9(
    const float* __restrict__ Z,
    const u32* __restrict__ W8,    // packed int8 weights (256 KB)
    const float* __restrict__ zsc, // [1024] per-row z scales
    float* __restrict__ Y,
    const float* __restrict__ RES,
    int d){
  extern __shared__ u32 dyn[];
  u32* wl = dyn;                   // NC*2048 u32 cached weights
  u32* h8 = dyn + NC*2048;         // 2 x 64 u32 (double-buffered int8 h)
  const int tid = threadIdx.x;
  const int chain = blockIdx.x;
  const int j = chain % 10;
  const int r = chain / 10;
  const int ns = (273 - r + d - 1)/d;
  const int kg = tid >> 2;
  const int js = tid & 3;
  const bool comb = (js == 0);
  const uint4* Wg = (const uint4*)W8;

  // one-time staging (coalesced)
  #pragma unroll
  for(int c=0;c<NC;c++)
    ((uint4*)wl)[c*512 + tid] = Wg[c*512 + tid];
  if(tid < 64) h8[tid] = 0u;       // zero buffer 0
  // per-thread row scales: rows rr*128+kg
  float scr[8];
  #pragma unroll
  for(int rr=0;rr<8;rr++) scr[rr] = zsc[rr*128 + kg];
  float cst0 = 0.f, cst1 = 0.f;
  __syncthreads();

  int t = r;
  for(int s=0; s<ns; s++, t+=d){
    const size_t row = (size_t)(t*10 + j);
    // prefetch Z/RES (combine lanes only; consumed after the dots)
    float zv[8]; float rv0=0.f, rv1=0.f;
    if(comb){
      const float* zb = Z + row*1024;
      #pragma unroll
      for(int g=0;g<4;g++){
        zv[2*g]   = zb[g*256 + kg];
        zv[2*g+1] = zb[g*256 + 128 + kg];
      }
      if(RES){ rv0 = RES[row*256 + kg]; rv1 = RES[row*256 + 128 + kg]; }
    }
    // read h (buffer s&1)
    const uint4* hq4 = (const uint4*)(h8 + (s&1)*64);
    uint4 hq0 = hq4[js*4+0], hq1 = hq4[js*4+1];
    uint4 hq2 = hq4[js*4+2], hq3 = hq4[js*4+3];
    int a[8];
    #pragma unroll
    for(int rr=0;rr<8;rr++) a[rr]=0;
    // streamed combos first (issue global loads early), then cached
    #pragma unroll
    for(int ci=0; ci<32; ci++){
      const int c = (ci + NC) & 31;
      const int rr = c >> 2, q = c & 3;
      uint4 w = (c < NC) ? ((const uint4*)wl)[c*512 + tid]
                         : Wg[c*512 + tid];
      uint4 h4 = (q==0)?hq0:(q==1)?hq1:(q==2)?hq2:hq3;
      int acc = a[rr];
      acc = dot4(w.x, h4.x, acc);
      acc = dot4(w.y, h4.y, acc);
      acc = dot4(w.z, h4.z, acc);
      acc = dot4(w.w, h4.w, acc);
      a[rr] = acc;
    }
    // quad reduction over js (lanes l^1, l^2)
    #pragma unroll
    for(int rr=0;rr<8;rr++){
      a[rr] += __shfl_xor(a[rr], 1);
      a[rr] += __shfl_xor(a[rr], 2);
    }
    if(comb){
      // unit u0=kg: gate rows rr=0,2,4,6 ; unit u1=kg+128: rr=1,3,5,7
      float zi0 = zv[0] + scr[0]*(float)a[0];
      float zi1 = zv[1] + scr[1]*(float)a[1];
      float zf0 = zv[2] + scr[2]*(float)a[2];
      float zf1 = zv[3] + scr[3]*(float)a[3];
      float zg0 = zv[4] + scr[4]*(float)a[4];
      float zg1 = zv[5] + scr[5]*(float)a[5];
      float zo0 = zv[6] + scr[6]*(float)a[6];
      float zo1 = zv[7] + scr[7]*(float)a[7];
      float c0 = sigf(zf0)*cst0 + sigf(zi0)*tanh_(zg0);
      float h0 = sigf(zo0)*tanh_(c0);
      float c1 = sigf(zf1)*cst1 + sigf(zi1)*tanh_(zg1);
      float h1 = sigf(zo1)*tanh_(c1);
      cst0 = c0; cst1 = c1;
      int q0 = max(-127, min(127, __float2int_rn(h0*127.f)));
      int q1 = max(-127, min(127, __float2int_rn(h1*127.f)));
      signed char* hb = (signed char*)(h8 + ((s+1)&1)*64);
      hb[kg]       = (signed char)q0;
      hb[kg + 128] = (signed char)q1;
      Y[row*256 + kg]       = h0 + rv0;
      Y[row*256 + 128 + kg] = h1 + rv1;
    }
    __syncthreads();
  }
}

// ---- fused head + all remaining outputs ----
__global__ __launch_bounds__(256) void k_headout(const float* __restrict__ Y4,
    const float* __restrict__ LWT,  // [256][256] f32 (linWT [f][u])
    const float* __restrict__ lb,
    const float* __restrict__ SWT,  // [256][28] f32  (scoreT [f][o])
    const float* __restrict__ sb,
    const float* __restrict__ ST, const float* __restrict__ lvlT,
    const float* __restrict__ xT, const float* __restrict__ val,
    float* __restrict__ out){
  __shared__ float v [8][256];
  __shared__ float h2[8][256];
  const int tid = threadIdx.x;
  if(blockIdx.x >= 342){
    int i = (blockIdx.x - 342)*256 + tid;
    if(i < N_O0){                        // actual_values
      int o = i % 28;
      int b = (i/28) % 128;
      int t = i/(28*128);
      int c = 28 + t + o;
      out[878080 + i] = xT[c*128+b] / ST[c*128+b] / lvlT[(27+t)*128+b];
    } else {
      i -= N_O0;
      if(i < 3584){                      // hav + hav_norm
        int b = i/28, o = i%28;
        int col = (o < 21) ? (286+o) : (279+o);
        float Sm = ST[col*128 + b];
        float lv = lvlT[299*128 + b];
        out[2738176 + i] = val[i];
        out[2741760 + i] = val[i] / Sm / lv;
      }
    }
    return;
  }
  const int m0 = blockIdx.x*8;
  for(int p=0;p<8;p++){
    int m = m0+p;
    v[p][tid] = (m<NM) ? Y4[m*256+tid] : 0.0f;
  }
  __syncthreads();
  float acc[8];
  float bz = lb[tid];
  #pragma unroll
  for(int p=0;p<8;p++) acc[p]=bz;
  #pragma unroll 4
  for(int f=0; f<256; f++){
    float w = LWT[f*256+tid];
    #pragma unroll
    for(int p=0;p<8;p++) acc[p] += w * v[p][f];
  }
  #pragma unroll
  for(int p=0;p<8;p++) h2[p][tid] = tanh_(acc[p]);
  __syncthreads();
  if(tid < 224){
    int o = tid % 28, p = tid / 28;
    int m = m0 + p;
    if(m < NM){
      float a = sb[o];
      for(int f=0; f<256; f++) a += SWT[f*28+o] * h2[p][f];
      int t = m / 10, j = m - t*10;
      float* o0 = out;                 // prediction_values (245,128,28)
      float* o3 = out + 1759744;       // rnn_out (273,128,28)
      for(int b=j; b<128; b+=10){
        size_t idx = (size_t)t*3584 + b*28 + o;
        o3[idx] = a;
        if(t < 245) o0[idx] = a;
      }
      if(t == 272){
        int col = (o < 21) ? (286+o) : (279+o);
        float* o2 = out + 1756160;     // holdout_prediction (128,28)
        for(int b=j; b<128; b+=10){
          float hv = a * ST[col*128 + b] * lvlT[299*128 + b];
          o2[b*28 + o] = (hv > 0.0f) ? hv : 0.0f;
        }
      }
    }
  }
}

extern "C" void kernel_launch(void* const* d_in, const int* in_sizes, int n_in,
                              void* d_out, int out_size, void* d_ws, size_t ws_size,
                              hipStream_t stream){
  (void)in_sizes; (void)n_in; (void)out_size; (void)ws_size;
  const float* x     = (const float*)d_in[0];
  const float* val   = (const float*)d_in[1];
  const float* alpha = (const float*)d_in[2];
  const float* gamma = (const float*)d_in[3];
  const float* iseas = (const float*)d_in[4];
  const float* cats  = (const float*)d_in[5];
  const float* mp    = (const float*)d_in[6];
  const float* Wih[4]  = {(const float*)d_in[7],  (const float*)d_in[10], (const float*)d_in[13], (const float*)d_in[16]};
  const float* Whh[4]  = {(const float*)d_in[8],  (const float*)d_in[11], (const float*)d_in[14], (const float*)d_in[17]};
  const float* bias[4] = {(const float*)d_in[9],  (const float*)d_in[12], (const float*)d_in[15], (const float*)d_in[18]};
  const float* linW  = (const float*)d_in[19];
  const float* linb  = (const float*)d_in[20];
  const float* scW   = (const float*)d_in[21];
  const float* scb   = (const float*)d_in[22];

  // ---- workspace layout ----
  float* Fw   = (float*)d_ws;
  float* ST   = Fw;                 // 39296
  float* lvlT = ST   + 39296;       // 38400
  float* xT   = lvlT + 38400;       // 38400
  float* xz   = xT   + 38400;       // 2795520
  float* yA   = xz   + 2795520;     // 698880  (L1 out / L3 out / L4 out)
  float* yB   = yA   + 698880;      // 698880  (L2 out, residual)
  float* wihT[4];
  wihT[0] = yB + 698880;            // 50176
  wihT[1] = wihT[0] + 50176;        // 262144
  wihT[2] = wihT[1] + 262144;
  wihT[3] = wihT[2] + 262144;
  float* linWT = wihT[3] + 262144;  // 65536
  float* scT   = linWT + 65536;     // 7168
  float* zsc   = scT   + 7168;      // 4096 (4 layers x 1024)
  u32*   W8all = (u32*)(zsc + 4096);// 4 x 65536 u32 = 1 MB

  // ---- dynamic-LDS budget for the big-cache scan variant ----
  const int sm13 = 13*8192 + 512;   // 13 combos + 2x64 u32 h
  const int sm7  = 7*8192 + 512;
  hipError_t ae = hipFuncSetAttribute((const void*)k_scan9<13>,
                    hipFuncAttributeMaxDynamicSharedMemorySize, sm13);
  const bool big = (ae == hipSuccess);

  // ---- prep: xT + transposes + row scales ----
  k_prep<<<3718, 256, 0, stream>>>(x, xT,
      Wih[0], wihT[0], Wih[1], wihT[1], Wih[2], wihT[2], Wih[3], wihT[3],
      linW, linWT, scW, scT,
      Whh[0], Whh[1], Whh[2], Whh[3], zsc);

  // ---- int8 pack + ES scan ----
  k_packes<<<1025, 256, 0, stream>>>(Whh[0], Whh[1], Whh[2], Whh[3], zsc, W8all,
                                     xT, alpha, gamma, iseas, ST, lvlT);

  // ---- 4 LSTM layers: Wih GEMM (win folded into L1) + int8 scan ----
  const int    dlt[4]    = {1, 2, 2, 6};
  const int    chains[4] = {10, 20, 20, 60};
  const float* Xin[4]    = {nullptr, yA, yB, yA};
  float*       Yout[4]   = {yA, yB, yA, yA};
  for(int l=0;l<4;l++){
    if(l == 0)
      k_gemm1<<<(NM+7)/8, 256, 0, stream>>>(xT, ST, lvlT, cats, mp,
                                            wihT[0], bias[0], xz);
    else
      k_gemm<<<(NM+7)/8, 256, 0, stream>>>(Xin[l], wihT[l], bias[l], xz);
    const float* res = (l==3) ? yB : (const float*)nullptr;
    if(big)
      k_scan9<13><<<chains[l], 512, sm13, stream>>>(xz, W8all + l*65536,
                                        zsc + l*1024, Yout[l], res, dlt[l]);
    else
      k_scan9<7><<<chains[l], 512, sm7, stream>>>(xz, W8all + l*65536,
                                        zsc + l*1024, Yout[l], res, dlt[l]);
  }

  // ---- fused head + outputs (+ actual_values + hav) ----
  k_headout<<<342 + (N_O0 + 3584 + 255)/256, 256, 0, stream>>>(
      yA, linWT, linb, scT, scb, ST, lvlT, xT, val, (float*)d_out);
}

// Round 13
// 1046.718 us; speedup vs baseline: 1.4114x; 1.4114x over previous
//
#include <hip/hip_runtime.h>

typedef unsigned short u16;
typedef unsigned int   u32;

static __device__ __forceinline__ float sigf (float x){ return 1.0f/(1.0f+__expf(-x)); }
static __device__ __forceinline__ float tanh_(float x){ return 2.0f/(1.0f+__expf(-2.0f*x)) - 1.0f; }

// sizes
#define NM 2730            // 273*10 distinct (t, j=b%10) rows
#define N_O0 878080        // 245*128*28
#define N_O3 978432        // 273*128*28

static __device__ __forceinline__ int dot4(u32 a, u32 b, int acc){
#if __has_builtin(__builtin_amdgcn_sdot4)
  return __builtin_amdgcn_sdot4((int)a, (int)b, acc, false);
#else
  int s = acc;
  #pragma unroll
  for(int i=0;i<4;i++){
    int av = (int)((signed char)((a >> (8*i)) & 0xffu));
    int bv = (int)((signed char)((b >> (8*i)) & 0xffu));
    s += av*bv;
  }
  return s;
#endif
}

// ---- fused prep: xT + 6 transposes + Whh row scales ----
__global__ __launch_bounds__(256) void k_prep(
    const float* __restrict__ x,     float* __restrict__ xT,
    const float* __restrict__ wi0,   float* __restrict__ wT0,
    const float* __restrict__ wi1,   float* __restrict__ wT1,
    const float* __restrict__ wi2,   float* __restrict__ wT2,
    const float* __restrict__ wi3,   float* __restrict__ wT3,
    const float* __restrict__ lw,    float* __restrict__ lwT,
    const float* __restrict__ sw,    float* __restrict__ swT,
    const float* __restrict__ h0, const float* __restrict__ h1,
    const float* __restrict__ h2, const float* __restrict__ h3,
    float* __restrict__ zsc){
  int i = blockIdx.x*256 + threadIdx.x;
  if(i < 38400){                    // xT
    int t = i >> 7, b = i & 127;
    xT[i] = x[b*300 + t];
    return;
  }
  i -= 38400;
  if(i < 50176){ int c=i/1024, r=i-c*1024; wT0[i] = wi0[r*49 + c];  return; }
  i -= 50176;
  if(i < 262144){ int c=i>>10, r=i&1023; wT1[i] = wi1[r*256 + c];   return; }
  i -= 262144;
  if(i < 262144){ int c=i>>10, r=i&1023; wT2[i] = wi2[r*256 + c];   return; }
  i -= 262144;
  if(i < 262144){ int c=i>>10, r=i&1023; wT3[i] = wi3[r*256 + c];   return; }
  i -= 262144;
  if(i < 65536){ int c=i>>8, r=i&255; lwT[i] = lw[r*256 + c];       return; }
  i -= 65536;
  if(i < 7168){ int c=i/28, r=i-c*28; swT[i] = sw[r*256 + c];       return; }
  i -= 7168;
  if(i < 4096){                     // per-row absmax scale (int8)
    int l = i >> 10, r = i & 1023;
    const float* W = (l==0)?h0:(l==1)?h1:(l==2)?h2:h3;
    const float4* p = (const float4*)(W + (size_t)r*256);
    float m = 0.f;
    #pragma unroll 8
    for(int q=0;q<64;q++){
      float4 v = p[q];
      m = fmaxf(m, fmaxf(fmaxf(fabsf(v.x),fabsf(v.y)), fmaxf(fabsf(v.z),fabsf(v.w))));
    }
    zsc[i] = fmaxf(m, 1e-20f) * (1.0f/16129.0f);   // rowmax/(127*127)
  }
}

// ---- fused int8 pack + ES scan (R11 pack layout) ----
// per-layer u32 idx uidx: dw=uidx&3, kg=(uidx>>2)&127, q=(uidx>>9)&3,
// rr=(uidx>>11)&7, js=uidx>>14 ; row=rr*128+kg ; k0=js*64+q*16+dw*4
__global__ __launch_bounds__(256) void k_packes(
    const float* __restrict__ h0, const float* __restrict__ h1,
    const float* __restrict__ h2, const float* __restrict__ h3,
    const float* __restrict__ zsc, u32* __restrict__ W8,
    const float* __restrict__ xT, const float* __restrict__ alpha,
    const float* __restrict__ gamma, const float* __restrict__ iseas,
    float* __restrict__ ST, float* __restrict__ lvlT){
  if(blockIdx.x < 1024){
    int i = blockIdx.x*256 + threadIdx.x;      // 0..262143
    int l = i >> 16;
    int uidx = i & 65535;
    int dw = uidx & 3;
    int kg = (uidx >> 2) & 127;
    int q  = (uidx >> 9) & 3;
    int rr = (uidx >> 11) & 7;
    int js = uidx >> 14;
    int row = rr*128 + kg;
    int k0  = js*64 + q*16 + dw*4;
    const float* W = (l==0)?h0:(l==1)?h1:(l==2)?h2:h3;
    float inv = 1.0f / (zsc[l*1024 + row] * 127.0f);
    u32 out = 0;
    #pragma unroll
    for(int b=0;b<4;b++){
      float v = W[(size_t)row*256 + k0 + b];
      int q8 = max(-127, min(127, __float2int_rn(v * inv)));
      out |= ((u32)(q8 & 0xff)) << (8*b);
    }
    W8[i] = out;
    return;
  }
  // ES scan (block 1024, threads 0..127)
  int b = threadIdx.x;
  if(b >= 128) return;
  float a = sigf(alpha[b]);
  float g = sigf(gamma[b]);
  float S0[7];
  #pragma unroll
  for(int i=0;i<7;i++){ S0[i] = __expf(iseas[b*7+i]); ST[i*128+b] = S0[i]; }
  ST[7*128+b] = S0[0];
  float q0=S0[1],q1=S0[2],q2=S0[3],q3=S0[4],q4=S0[5],q5=S0[6],q6=S0[0];
  float lvl = xT[b]/S0[0];
  lvlT[b] = lvl;
  for(int t=1;t<300;t++){
    float xt = xT[t*128+b];
    float s  = q0;
    lvl = a*(xt/s) + (1.0f-a)*lvl;
    float sn = g*(xt/lvl) + (1.0f-g)*s;
    q0=q1;q1=q2;q2=q3;q3=q4;q4=q5;q5=q6;q6=sn;
    lvlT[t*128+b]   = lvl;
    ST[(t+7)*128+b] = sn;
  }
}

// ---- gemm for layer 1: window_input built on the fly in staging ----
__global__ __launch_bounds__(256) void k_gemm1(
    const float* __restrict__ xT, const float* __restrict__ ST,
    const float* __restrict__ lvlT, const float* __restrict__ cats,
    const float* __restrict__ mp,
    const float* __restrict__ WT,   // [49][1024] f32
    const float* __restrict__ bias, // [1024] f32
    float* __restrict__ Z){
  __shared__ float Xs[8][52];
  const int tid = threadIdx.x;
  const int m0 = blockIdx.x*8;
  for(int idx=tid; idx<8*49; idx+=256){
    int p = idx/49, f = idx - p*49;
    int m = m0+p;
    float v = 0.f;
    if(m < NM){
      int tt = m/10, jj = m - (m/10)*10;
      if(f < 28){
        int c = tt + f;
        v = xT[c*128 + jj] / ST[c*128 + jj] / lvlT[(tt+27)*128 + jj];
      } else if(f < 48){
        v = cats[jj*20 + (f-28)];
      } else {
        v = mp[0];
      }
    }
    Xs[p][f] = v;
  }
  __syncthreads();
  float acc0[8], acc1[8], acc2[8], acc3[8];
  {
    float b0 = bias[tid];
    float b1 = bias[tid+256];
    float b2 = bias[tid+512];
    float b3 = bias[tid+768];
    #pragma unroll
    for(int p=0;p<8;p++){ acc0[p]=b0; acc1[p]=b1; acc2[p]=b2; acc3[p]=b3; }
  }
  #pragma unroll 7
  for(int f=0; f<49; f++){
    float w0 = WT[f*1024 + tid      ];
    float w1 = WT[f*1024 + tid+256  ];
    float w2 = WT[f*1024 + tid+512  ];
    float w3 = WT[f*1024 + tid+768  ];
    #pragma unroll
    for(int p=0;p<8;p++){
      float xv = Xs[p][f];
      acc0[p] += w0*xv; acc1[p] += w1*xv; acc2[p] += w2*xv; acc3[p] += w3*xv;
    }
  }
  for(int p=0;p<8;p++){
    int m = m0+p;
    if(m < NM){
      float* zb = Z + m*1024 + tid;
      zb[0]=acc0[p]; zb[256]=acc1[p]; zb[512]=acc2[p]; zb[768]=acc3[p];
    }
  }
}

// ---- batched xz = X @ WihT + b (F=256 layers) ----
__global__ __launch_bounds__(256) void k_gemm(const float* __restrict__ X,
                                              const float* __restrict__ WT,   // [256][1024] f32
                                              const float* __restrict__ bias, // [1024] f32
                                              float* __restrict__ Z){
  __shared__ float Xs[8][256];
  const int tid = threadIdx.x;
  const int m0 = blockIdx.x*8;
  for(int p=0;p<8;p++){
    int m = m0+p;
    Xs[p][tid] = (m < NM) ? X[m*256+tid] : 0.0f;
  }
  __syncthreads();
  float acc0[8], acc1[8], acc2[8], acc3[8];
  {
    float b0 = bias[tid];
    float b1 = bias[tid+256];
    float b2 = bias[tid+512];
    float b3 = bias[tid+768];
    #pragma unroll
    for(int p=0;p<8;p++){ acc0[p]=b0; acc1[p]=b1; acc2[p]=b2; acc3[p]=b3; }
  }
  #pragma unroll 4
  for(int f=0; f<256; f++){
    float w0 = WT[f*1024 + tid      ];
    float w1 = WT[f*1024 + tid+256  ];
    float w2 = WT[f*1024 + tid+512  ];
    float w3 = WT[f*1024 + tid+768  ];
    #pragma unroll
    for(int p=0;p<8;p++){
      float xv = Xs[p][f];
      acc0[p] += w0*xv; acc1[p] += w1*xv; acc2[p] += w2*xv; acc3[p] += w3*xv;
    }
  }
  for(int p=0;p<8;p++){
    int m = m0+p;
    if(m < NM){
      float* zb = Z + m*1024 + tid;
      zb[0]=acc0[p]; zb[256]=acc1[p]; zb[512]=acc2[p]; zb[768]=acc3[p];
    }
  }
}

// ---- LSTM scan vA: EXACT R11 structure (thread kg=tid&127, js=tid>>7,
// zp LDS reduction, 2 barriers, Z/RES prefetch) — only the weight cache
// grows: NC of 32 combos in dynamic LDS (combo c = q*8+rr, q=c>>3, rr=c&7),
// rest streamed from L2. NC=5 == R11 byte-for-byte behavior.
template<int NC>
__global__ __launch_bounds__(512) void k_scanA(
    const float* __restrict__ Z,
    const u32* __restrict__ W8,    // packed int8 weights (256 KB)
    const float* __restrict__ zsc, // [1024] per-row z scales
    float* __restrict__ Y,
    const float* __restrict__ RES,
    int d){
  extern __shared__ u32 wl[];            // NC*2048 u32 cached weights
  __shared__ __align__(16) u32 h8[64];   // 256 int8 h
  __shared__ int   zp[4][1024];          // 16 KB partials
  __shared__ float sc[1024];             // 4 KB row scales
  const int tid = threadIdx.x;
  const int chain = blockIdx.x;
  const int j = chain % 10;
  const int r = chain / 10;
  const int ns = (273 - r + d - 1)/d;
  const int kg = tid & 127;
  const int js = tid >> 7;
  const uint4* Wb = (const uint4*)W8 + (size_t)js*4096 + kg;
  const uint4* hq = (const uint4*)h8 + js*4;
  uint4* wl4 = (uint4*)wl;

  for(int i=tid;i<1024;i+=512) sc[i] = zsc[i];
  #pragma unroll
  for(int c=0;c<NC;c++)
    wl4[c*512 + tid] = Wb[(c&7)*512 + (c>>3)*128];
  if(tid < 64) h8[tid] = 0u;
  float cst = 0.0f;
  __syncthreads();

  int t = r;
  for(int s=0; s<ns; s++, t+=d){
    const size_t row = (size_t)(t*10 + j);
    float zv0=0.f, zv1=0.f, zv2=0.f, zv3=0.f, rv=0.f;
    if(tid < 256){                       // prefetch (consumed after barrier)
      const float* zb = Z + row*1024;
      zv0 = zb[tid]; zv1 = zb[tid+256]; zv2 = zb[tid+512]; zv3 = zb[tid+768];
      if(RES) rv = RES[row*256 + tid];
    }
    int a0=0,a1=0,a2=0,a3=0,a4=0,a5=0,a6=0,a7=0;
    #pragma unroll
    for(int q=0;q<4;q++){
      uint4 h4 = hq[q];                  // broadcast: 16 h int8
      #pragma unroll
      for(int rr=0;rr<8;rr++){
        const int c = q*8 + rr;
        uint4 w = (c < NC) ? wl4[c*512 + tid] : Wb[rr*512 + q*128];
        int* ap = (rr==0)?&a0:(rr==1)?&a1:(rr==2)?&a2:(rr==3)?&a3:
                  (rr==4)?&a4:(rr==5)?&a5:(rr==6)?&a6:&a7;
        int acc = *ap;
        acc = dot4(w.x, h4.x, acc);
        acc = dot4(w.y, h4.y, acc);
        acc = dot4(w.z, h4.z, acc);
        acc = dot4(w.w, h4.w, acc);
        *ap = acc;
      }
    }
    zp[js][       kg] = a0;
    zp[js][128  + kg] = a1;
    zp[js][256  + kg] = a2;
    zp[js][384  + kg] = a3;
    zp[js][512  + kg] = a4;
    zp[js][640  + kg] = a5;
    zp[js][768  + kg] = a6;
    zp[js][896  + kg] = a7;
    __syncthreads();
    if(tid < 256){
      const int u = tid;
      int si = zp[0][u]     + zp[1][u]     + zp[2][u]     + zp[3][u];
      int sf = zp[0][u+256] + zp[1][u+256] + zp[2][u+256] + zp[3][u+256];
      int sg = zp[0][u+512] + zp[1][u+512] + zp[2][u+512] + zp[3][u+512];
      int so = zp[0][u+768] + zp[1][u+768] + zp[2][u+768] + zp[3][u+768];
      float zi = zv0 + sc[u]     * (float)si;
      float zf = zv1 + sc[u+256] * (float)sf;
      float zg = zv2 + sc[u+512] * (float)sg;
      float zo = zv3 + sc[u+768] * (float)so;
      float c  = sigf(zf)*cst + sigf(zi)*tanh_(zg);
      float h  = sigf(zo)*tanh_(c);
      cst = c;
      int hqi = __float2int_rn(h * 127.0f);
      hqi = max(-127, min(127, hqi));
      ((signed char*)h8)[u] = (signed char)hqi;
      Y[row*256 + u] = h + rv;
    }
    __syncthreads();
  }
}

// ---- fused head + all remaining outputs ----
__global__ __launch_bounds__(256) void k_headout(const float* __restrict__ Y4,
    const float* __restrict__ LWT,  // [256][256] f32 (linWT [f][u])
    const float* __restrict__ lb,
    const float* __restrict__ SWT,  // [256][28] f32  (scoreT [f][o])
    const float* __restrict__ sb,
    const float* __restrict__ ST, const float* __restrict__ lvlT,
    const float* __restrict__ xT, const float* __restrict__ val,
    float* __restrict__ out){
  __shared__ float v [8][256];
  __shared__ float h2[8][256];
  const int tid = threadIdx.x;
  if(blockIdx.x >= 342){
    int i = (blockIdx.x - 342)*256 + tid;
    if(i < N_O0){                        // actual_values
      int o = i % 28;
      int b = (i/28) % 128;
      int t = i/(28*128);
      int c = 28 + t + o;
      out[878080 + i] = xT[c*128+b] / ST[c*128+b] / lvlT[(27+t)*128+b];
    } else {
      i -= N_O0;
      if(i < 3584){                      // hav + hav_norm
        int b = i/28, o = i%28;
        int col = (o < 21) ? (286+o) : (279+o);
        float Sm = ST[col*128 + b];
        float lv = lvlT[299*128 + b];
        out[2738176 + i] = val[i];
        out[2741760 + i] = val[i] / Sm / lv;
      }
    }
    return;
  }
  const int m0 = blockIdx.x*8;
  for(int p=0;p<8;p++){
    int m = m0+p;
    v[p][tid] = (m<NM) ? Y4[m*256+tid] : 0.0f;
  }
  __syncthreads();
  float acc[8];
  float bz = lb[tid];
  #pragma unroll
  for(int p=0;p<8;p++) acc[p]=bz;
  #pragma unroll 4
  for(int f=0; f<256; f++){
    float w = LWT[f*256+tid];
    #pragma unroll
    for(int p=0;p<8;p++) acc[p] += w * v[p][f];
  }
  #pragma unroll
  for(int p=0;p<8;p++) h2[p][tid] = tanh_(acc[p]);
  __syncthreads();
  if(tid < 224){
    int o = tid % 28, p = tid / 28;
    int m = m0 + p;
    if(m < NM){
      float a = sb[o];
      for(int f=0; f<256; f++) a += SWT[f*28+o] * h2[p][f];
      int t = m / 10, j = m - t*10;
      float* o0 = out;                 // prediction_values (245,128,28)
      float* o3 = out + 1759744;       // rnn_out (273,128,28)
      for(int b=j; b<128; b+=10){
        size_t idx = (size_t)t*3584 + b*28 + o;
        o3[idx] = a;
        if(t < 245) o0[idx] = a;
      }
      if(t == 272){
        int col = (o < 21) ? (286+o) : (279+o);
        float* o2 = out + 1756160;     // holdout_prediction (128,28)
        for(int b=j; b<128; b+=10){
          float hv = a * ST[col*128 + b] * lvlT[299*128 + b];
          o2[b*28 + o] = (hv > 0.0f) ? hv : 0.0f;
        }
      }
    }
  }
}

extern "C" void kernel_launch(void* const* d_in, const int* in_sizes, int n_in,
                              void* d_out, int out_size, void* d_ws, size_t ws_size,
                              hipStream_t stream){
  (void)in_sizes; (void)n_in; (void)out_size; (void)ws_size;
  const float* x     = (const float*)d_in[0];
  const float* val   = (const float*)d_in[1];
  const float* alpha = (const float*)d_in[2];
  const float* gamma = (const float*)d_in[3];
  const float* iseas = (const float*)d_in[4];
  const float* cats  = (const float*)d_in[5];
  const float* mp    = (const float*)d_in[6];
  const float* Wih[4]  = {(const float*)d_in[7],  (const float*)d_in[10], (const float*)d_in[13], (const float*)d_in[16]};
  const float* Whh[4]  = {(const float*)d_in[8],  (const float*)d_in[11], (const float*)d_in[14], (const float*)d_in[17]};
  const float* bias[4] = {(const float*)d_in[9],  (const float*)d_in[12], (const float*)d_in[15], (const float*)d_in[18]};
  const float* linW  = (const float*)d_in[19];
  const float* linb  = (const float*)d_in[20];
  const float* scW   = (const float*)d_in[21];
  const float* scb   = (const float*)d_in[22];

  // ---- workspace layout ----
  float* Fw   = (float*)d_ws;
  float* ST   = Fw;                 // 39296
  float* lvlT = ST   + 39296;       // 38400
  float* xT   = lvlT + 38400;       // 38400
  float* xz   = xT   + 38400;       // 2795520
  float* yA   = xz   + 2795520;     // 698880  (L1 out / L3 out / L4 out)
  float* yB   = yA   + 698880;      // 698880  (L2 out, residual)
  float* wihT[4];
  wihT[0] = yB + 698880;            // 50176
  wihT[1] = wihT[0] + 50176;        // 262144
  wihT[2] = wihT[1] + 262144;
  wihT[3] = wihT[2] + 262144;
  float* linWT = wihT[3] + 262144;  // 65536
  float* scT   = linWT + 65536;     // 7168
  float* zsc   = scT   + 7168;      // 4096 (4 layers x 1024)
  u32*   W8all = (u32*)(zsc + 4096);// 4 x 65536 u32 = 1 MB

  // ---- dynamic-LDS budget for the big-cache scan variant ----
  const int smBig = 12*8192;        // 96 KB dynamic (+20.25 KB static)
  const int smSml = 5*8192;         // 40 KB dynamic == R11 total
  hipError_t ae = hipFuncSetAttribute((const void*)k_scanA<12>,
                    hipFuncAttributeMaxDynamicSharedMemorySize, smBig);
  const bool big = (ae == hipSuccess);

  // ---- prep: xT + transposes + row scales ----
  k_prep<<<3718, 256, 0, stream>>>(x, xT,
      Wih[0], wihT[0], Wih[1], wihT[1], Wih[2], wihT[2], Wih[3], wihT[3],
      linW, linWT, scW, scT,
      Whh[0], Whh[1], Whh[2], Whh[3], zsc);

  // ---- int8 pack + ES scan ----
  k_packes<<<1025, 256, 0, stream>>>(Whh[0], Whh[1], Whh[2], Whh[3], zsc, W8all,
                                     xT, alpha, gamma, iseas, ST, lvlT);

  // ---- 4 LSTM layers: Wih GEMM (win folded into L1) + int8 scan ----
  const int    dlt[4]    = {1, 2, 2, 6};
  const int    chains[4] = {10, 20, 20, 60};
  const float* Xin[4]    = {nullptr, yA, yB, yA};
  float*       Yout[4]   = {yA, yB, yA, yA};
  for(int l=0;l<4;l++){
    if(l == 0)
      k_gemm1<<<(NM+7)/8, 256, 0, stream>>>(xT, ST, lvlT, cats, mp,
                                            wihT[0], bias[0], xz);
    else
      k_gemm<<<(NM+7)/8, 256, 0, stream>>>(Xin[l], wihT[l], bias[l], xz);
    const float* res = (l==3) ? yB : (const float*)nullptr;
    if(big)
      k_scanA<12><<<chains[l], 512, smBig, stream>>>(xz, W8all + l*65536,
                                        zsc + l*1024, Yout[l], res, dlt[l]);
    else
      k_scanA<5><<<chains[l], 512, smSml, stream>>>(xz, W8all + l*65536,
                                        zsc + l*1024, Yout[l], res, dlt[l]);
  }

  // ---- fused head + outputs (+ actual_values + hav) ----
  k_headout<<<342 + (N_O0 + 3584 + 255)/256, 256, 0, stream>>>(
      yA, linWT, linb, scT, scb, ST, lvlT, xT, val, (float*)d_out);
}